// Round 1
// baseline (848.837 us; speedup 1.0000x reference)
//
#include <hip/hip_runtime.h>
#include <hip/hip_bf16.h>

#define NN 100000
#define NE 1600000
#define NODE_D 64
#define EDGE_D 48
#define U_D 32
#define HID 128
#define OUT_D 64
#define BN 64

__device__ __forceinline__ unsigned short f2b(float f) {
  union { __hip_bfloat16 h; unsigned short u; } v;
  v.h = __float2bfloat16(f);
  return v.u;
}
__device__ __forceinline__ float blo(unsigned int pk) {
  union { unsigned int u; float f; } v; v.u = pk << 16; return v.f;
}
__device__ __forceinline__ float bhi(unsigned int pk) {
  union { unsigned int u; float f; } v; v.u = pk & 0xffff0000u; return v.f;
}

__global__ __launch_bounds__(256) void scatter_kernel(
    const float* __restrict__ ea, const int* __restrict__ src_idx,
    float* __restrict__ sums, float* __restrict__ cnt) {
  unsigned i = blockIdx.x * 256u + threadIdx.x;
  const unsigned total = (unsigned)NE * EDGE_D;
  if (i >= total) return;
  unsigned e = i / EDGE_D;
  unsigned f = i - e * EDGE_D;
  int s = src_idx[e];
  atomicAdd(&sums[(size_t)s * EDGE_D + f], ea[i]);
  if (f == 0) atomicAdd(&cnt[s], 1.0f);
}

__global__ __launch_bounds__(BN) void mlp_kernel(
    const float* __restrict__ x, const float* __restrict__ sums,
    const float* __restrict__ cnt, const float* __restrict__ u,
    const int* __restrict__ batch,
    const float* __restrict__ W1, const float* __restrict__ b1,
    const float* __restrict__ W2, const float* __restrict__ b2,
    const float* __restrict__ W3, const float* __restrict__ b3,
    float* __restrict__ out) {
  __shared__ unsigned short comb[BN][146];  // 144 pad->146 (odd word stride)
  __shared__ unsigned short hb[BN][130];    // 128 pad->130
  const int tid = threadIdx.x;
  const int node0 = blockIdx.x * BN;

  // ---- coalesced staging of comb = [x | v_e | u[batch]] as bf16 ----
  for (int idx = tid; idx < BN * NODE_D; idx += BN) {
    int r = idx >> 6, c = idx & 63;
    int node = node0 + r;
    float v = (node < NN) ? x[(size_t)node * NODE_D + c] : 0.f;
    comb[r][c] = f2b(v);
  }
  for (int idx = tid; idx < BN * EDGE_D; idx += BN) {
    int r = idx / EDGE_D, c = idx - r * EDGE_D;
    int node = node0 + r;
    float v = 0.f;
    if (node < NN) v = sums[(size_t)node * EDGE_D + c] / fmaxf(cnt[node], 1.0f);
    comb[r][NODE_D + c] = f2b(v);
  }
  for (int idx = tid; idx < BN * U_D; idx += BN) {
    int r = idx >> 5, c = idx & 31;
    int node = node0 + r;
    float v = 0.f;
    if (node < NN) v = u[(size_t)batch[node] * U_D + c];
    comb[r][NODE_D + EDGE_D + c] = f2b(v);
  }
  __syncthreads();

  const int node = node0 + tid;
  if (node >= NN) return;

  // ---- stage 1: 144 -> 128, relu, into hb (bf16) ----
  for (int jt = 0; jt < HID / 16; ++jt) {
    float acc[16];
#pragma unroll
    for (int i = 0; i < 16; ++i) acc[i] = b1[jt * 16 + i];
#pragma unroll 4
    for (int k2 = 0; k2 < 72; ++k2) {
      unsigned int pk = *reinterpret_cast<const unsigned int*>(&comb[tid][2 * k2]);
      float c0 = blo(pk), c1 = bhi(pk);
      const float* w0 = &W1[(2 * k2) * HID + jt * 16];
      const float* w1 = w0 + HID;
#pragma unroll
      for (int i = 0; i < 16; ++i) acc[i] = fmaf(c0, w0[i], acc[i]);
#pragma unroll
      for (int i = 0; i < 16; ++i) acc[i] = fmaf(c1, w1[i], acc[i]);
    }
#pragma unroll
    for (int i = 0; i < 16; i += 2) {
      unsigned int pk = (unsigned)f2b(fmaxf(acc[i], 0.f)) |
                        ((unsigned)f2b(fmaxf(acc[i + 1], 0.f)) << 16);
      *reinterpret_cast<unsigned int*>(&hb[tid][jt * 16 + i]) = pk;
    }
  }

  // ---- stage 2: 128 -> 128, relu, into comb[tid][0..127] (bf16) ----
  for (int jt = 0; jt < HID / 16; ++jt) {
    float acc[16];
#pragma unroll
    for (int i = 0; i < 16; ++i) acc[i] = b2[jt * 16 + i];
#pragma unroll 4
    for (int k2 = 0; k2 < 64; ++k2) {
      unsigned int pk = *reinterpret_cast<const unsigned int*>(&hb[tid][2 * k2]);
      float c0 = blo(pk), c1 = bhi(pk);
      const float* w0 = &W2[(2 * k2) * HID + jt * 16];
      const float* w1 = w0 + HID;
#pragma unroll
      for (int i = 0; i < 16; ++i) acc[i] = fmaf(c0, w0[i], acc[i]);
#pragma unroll
      for (int i = 0; i < 16; ++i) acc[i] = fmaf(c1, w1[i], acc[i]);
    }
#pragma unroll
    for (int i = 0; i < 16; i += 2) {
      unsigned int pk = (unsigned)f2b(fmaxf(acc[i], 0.f)) |
                        ((unsigned)f2b(fmaxf(acc[i + 1], 0.f)) << 16);
      *reinterpret_cast<unsigned int*>(&comb[tid][jt * 16 + i]) = pk;
    }
  }

  // ---- stage 3: 128 -> 64, write f32 out ----
  for (int jt = 0; jt < OUT_D / 16; ++jt) {
    float acc[16];
#pragma unroll
    for (int i = 0; i < 16; ++i) acc[i] = b3[jt * 16 + i];
#pragma unroll 4
    for (int k2 = 0; k2 < 64; ++k2) {
      unsigned int pk = *reinterpret_cast<const unsigned int*>(&comb[tid][2 * k2]);
      float c0 = blo(pk), c1 = bhi(pk);
      const float* w0 = &W3[(2 * k2) * OUT_D + jt * 16];
      const float* w1 = w0 + OUT_D;
#pragma unroll
      for (int i = 0; i < 16; ++i) acc[i] = fmaf(c0, w0[i], acc[i]);
#pragma unroll
      for (int i = 0; i < 16; ++i) acc[i] = fmaf(c1, w1[i], acc[i]);
    }
    float4* o = reinterpret_cast<float4*>(&out[(size_t)node * OUT_D + jt * 16]);
    o[0] = make_float4(acc[0], acc[1], acc[2], acc[3]);
    o[1] = make_float4(acc[4], acc[5], acc[6], acc[7]);
    o[2] = make_float4(acc[8], acc[9], acc[10], acc[11]);
    o[3] = make_float4(acc[12], acc[13], acc[14], acc[15]);
  }
}

extern "C" void kernel_launch(void* const* d_in, const int* in_sizes, int n_in,
                              void* d_out, int out_size, void* d_ws, size_t ws_size,
                              hipStream_t stream) {
  const float* x   = (const float*)d_in[0];
  const int* ei    = (const int*)d_in[1];    // [2, NE]; row 0 = source nodes
  const float* ea  = (const float*)d_in[2];
  const float* u   = (const float*)d_in[3];
  const int* batch = (const int*)d_in[4];
  const float* W1  = (const float*)d_in[5];
  const float* b1  = (const float*)d_in[6];
  const float* W2  = (const float*)d_in[7];
  const float* b2  = (const float*)d_in[8];
  const float* W3  = (const float*)d_in[9];
  const float* b3  = (const float*)d_in[10];
  float* out = (float*)d_out;

  float* sums = (float*)d_ws;                     // NN*48 f32
  float* cnt  = sums + (size_t)NN * EDGE_D;       // NN f32

  hipMemsetAsync(d_ws, 0, ((size_t)NN * EDGE_D + NN) * sizeof(float), stream);

  {
    unsigned total = (unsigned)NE * EDGE_D;
    dim3 g((total + 255) / 256);
    scatter_kernel<<<g, dim3(256), 0, stream>>>(ea, ei, sums, cnt);
  }
  {
    dim3 g((NN + BN - 1) / BN);
    mlp_kernel<<<g, dim3(BN), 0, stream>>>(x, sums, cnt, u, batch,
                                           W1, b1, W2, b2, W3, b3, out);
  }
}

// Round 2
// 388.184 us; speedup vs baseline: 2.1867x; 2.1867x over previous
//
#include <hip/hip_runtime.h>
#include <hip/hip_bf16.h>

#define NN 100000
#define NE 1600000
#define NODE_D 64
#define EDGE_D 48
#define U_D 32
#define IN_D 144
#define HID 128
#define OUT_D 64
#define BM 64
#define S0 152   // act0 row stride (ushort cols): 304 B, 16B-aligned, bank-spread
#define S1 136   // act1 row stride: 272 B

typedef __attribute__((ext_vector_type(8))) short bf16x8;
typedef __attribute__((ext_vector_type(4))) float f32x4;

__device__ __forceinline__ short f2bs(float f) {
  union { __hip_bfloat16 h; short s; } v;
  v.h = __float2bfloat16(f);
  return v.s;
}

__device__ __forceinline__ void st4(unsigned short* p, float4 v) {
  unsigned a = (unsigned)(unsigned short)f2bs(v.x) | ((unsigned)(unsigned short)f2bs(v.y) << 16);
  unsigned b = (unsigned)(unsigned short)f2bs(v.z) | ((unsigned)(unsigned short)f2bs(v.w) << 16);
  *reinterpret_cast<uint2*>(p) = make_uint2(a, b);
}

__global__ __launch_bounds__(256) void scatter_kernel(
    const float* __restrict__ ea, const int* __restrict__ src_idx,
    float* __restrict__ sums, float* __restrict__ cnt) {
  unsigned i = blockIdx.x * 256u + threadIdx.x;
  const unsigned total = (unsigned)NE * EDGE_D;
  if (i >= total) return;
  unsigned e = i / EDGE_D;
  unsigned f = i - e * EDGE_D;
  int s = src_idx[e];
  atomicAdd(&sums[(size_t)s * EDGE_D + f], ea[i]);
  if (f == 0) atomicAdd(&cnt[s], 1.0f);
}

__global__ __launch_bounds__(256) void mlp_kernel(
    const float* __restrict__ x, const float* __restrict__ sums,
    const float* __restrict__ cnt, const float* __restrict__ u,
    const int* __restrict__ batch,
    const float* __restrict__ W1, const float* __restrict__ b1,
    const float* __restrict__ W2, const float* __restrict__ b2,
    const float* __restrict__ W3, const float* __restrict__ b3,
    float* __restrict__ out) {
  __shared__ unsigned short act0[BM][S0];  // comb (144 cols), later h2 (128 cols)
  __shared__ unsigned short act1[BM][S1];  // h1 (128 cols)

  const int tid = threadIdx.x;
  const int lane = tid & 63;
  const int wid = tid >> 6;
  const int lr = lane & 15;   // row-of-A / col-of-B within fragment
  const int lg = lane >> 4;   // k-group (0..3)
  const int node0 = blockIdx.x * BM;

  const bf16x8 az = {0, 0, 0, 0, 0, 0, 0, 0};

  // ---------------- stage comb = [x | v_e | u[batch]] as bf16 ----------------
  // x part: 64 rows x 16 float4
  for (int i = tid; i < BM * (NODE_D / 4); i += 256) {
    int r = i >> 4, q = i & 15;
    int node = node0 + r;
    float4 v = make_float4(0.f, 0.f, 0.f, 0.f);
    if (node < NN) v = reinterpret_cast<const float4*>(x)[(size_t)node * 16 + q];
    st4(&act0[r][q * 4], v);
  }
  // v_e part: 64 rows x 12 float4
  for (int i = tid; i < BM * (EDGE_D / 4); i += 256) {
    int r = i / 12, q = i - r * 12;
    int node = node0 + r;
    float4 v = make_float4(0.f, 0.f, 0.f, 0.f);
    if (node < NN) {
      float inv = 1.0f / fmaxf(cnt[node], 1.0f);
      float4 s = reinterpret_cast<const float4*>(sums)[(size_t)node * 12 + q];
      v = make_float4(s.x * inv, s.y * inv, s.z * inv, s.w * inv);
    }
    st4(&act0[r][NODE_D + q * 4], v);
  }
  // u part: 64 rows x 8 float4
  for (int i = tid; i < BM * (U_D / 4); i += 256) {
    int r = i >> 3, q = i & 7;
    int node = node0 + r;
    float4 v = make_float4(0.f, 0.f, 0.f, 0.f);
    if (node < NN) {
      int b = batch[node];
      v = reinterpret_cast<const float4*>(u)[(size_t)b * 8 + q];
    }
    st4(&act0[r][NODE_D + EDGE_D + q * 4], v);
  }
  __syncthreads();

  // ---------------- layer 1: [64,144] @ [144,128] + b1, relu -> act1 ----------------
  {
    const int n0 = wid * 32;
    bf16x8 wf[5][2];
#pragma unroll
    for (int t = 0; t < 5; ++t) {
#pragma unroll
      for (int nf = 0; nf < 2; ++nf) {
        const int kb = t * 32 + lg * 8;
        const int n = n0 + nf * 16 + lr;
        bf16x8 r = az;
#pragma unroll
        for (int j = 0; j < 8; ++j) {
          int k = kb + j;
          if (k < IN_D) r[j] = f2bs(W1[(size_t)k * HID + n]);
        }
        wf[t][nf] = r;
      }
    }
    float bias0 = b1[n0 + lr], bias1 = b1[n0 + 16 + lr];
    f32x4 acc[4][2];
#pragma unroll
    for (int mf = 0; mf < 4; ++mf) {
      acc[mf][0] = (f32x4){bias0, bias0, bias0, bias0};
      acc[mf][1] = (f32x4){bias1, bias1, bias1, bias1};
    }
#pragma unroll
    for (int t = 0; t < 5; ++t) {
#pragma unroll
      for (int mf = 0; mf < 4; ++mf) {
        bf16x8 a;
        if (t < 4) {
          a = *reinterpret_cast<const bf16x8*>(&act0[mf * 16 + lr][t * 32 + lg * 8]);
        } else {
          a = az;
          if (lg < 2)
            a = *reinterpret_cast<const bf16x8*>(&act0[mf * 16 + lr][128 + lg * 8]);
        }
        acc[mf][0] = __builtin_amdgcn_mfma_f32_16x16x32_bf16(a, wf[t][0], acc[mf][0], 0, 0, 0);
        acc[mf][1] = __builtin_amdgcn_mfma_f32_16x16x32_bf16(a, wf[t][1], acc[mf][1], 0, 0, 0);
      }
    }
#pragma unroll
    for (int mf = 0; mf < 4; ++mf)
#pragma unroll
      for (int nf = 0; nf < 2; ++nf)
#pragma unroll
        for (int r = 0; r < 4; ++r)
          act1[mf * 16 + lg * 4 + r][n0 + nf * 16 + lr] =
              (unsigned short)f2bs(fmaxf(acc[mf][nf][r], 0.f));
  }
  __syncthreads();

  // ---------------- layer 2: [64,128] @ [128,128] + b2, relu -> act0 ----------------
  {
    const int n0 = wid * 32;
    bf16x8 wf[4][2];
#pragma unroll
    for (int t = 0; t < 4; ++t) {
#pragma unroll
      for (int nf = 0; nf < 2; ++nf) {
        const int kb = t * 32 + lg * 8;
        const int n = n0 + nf * 16 + lr;
        bf16x8 r;
#pragma unroll
        for (int j = 0; j < 8; ++j) r[j] = f2bs(W2[(size_t)(kb + j) * HID + n]);
        wf[t][nf] = r;
      }
    }
    float bias0 = b2[n0 + lr], bias1 = b2[n0 + 16 + lr];
    f32x4 acc[4][2];
#pragma unroll
    for (int mf = 0; mf < 4; ++mf) {
      acc[mf][0] = (f32x4){bias0, bias0, bias0, bias0};
      acc[mf][1] = (f32x4){bias1, bias1, bias1, bias1};
    }
#pragma unroll
    for (int t = 0; t < 4; ++t) {
#pragma unroll
      for (int mf = 0; mf < 4; ++mf) {
        bf16x8 a = *reinterpret_cast<const bf16x8*>(&act1[mf * 16 + lr][t * 32 + lg * 8]);
        acc[mf][0] = __builtin_amdgcn_mfma_f32_16x16x32_bf16(a, wf[t][0], acc[mf][0], 0, 0, 0);
        acc[mf][1] = __builtin_amdgcn_mfma_f32_16x16x32_bf16(a, wf[t][1], acc[mf][1], 0, 0, 0);
      }
    }
    __syncthreads();  // everyone done reading act0 (layer-1 A) before overwrite
#pragma unroll
    for (int mf = 0; mf < 4; ++mf)
#pragma unroll
      for (int nf = 0; nf < 2; ++nf)
#pragma unroll
        for (int r = 0; r < 4; ++r)
          act0[mf * 16 + lg * 4 + r][n0 + nf * 16 + lr] =
              (unsigned short)f2bs(fmaxf(acc[mf][nf][r], 0.f));
  }
  __syncthreads();

  // ---------------- layer 3: [64,128] @ [128,64] + b3 -> out (f32) ----------------
  {
    const int n0 = wid * 16;
    bf16x8 wf[4];
#pragma unroll
    for (int t = 0; t < 4; ++t) {
      const int kb = t * 32 + lg * 8;
      const int n = n0 + lr;
      bf16x8 r;
#pragma unroll
      for (int j = 0; j < 8; ++j) r[j] = f2bs(W3[(size_t)(kb + j) * OUT_D + n]);
      wf[t] = r;
    }
    float bias = b3[n0 + lr];
    f32x4 acc[4];
#pragma unroll
    for (int mf = 0; mf < 4; ++mf) acc[mf] = (f32x4){bias, bias, bias, bias};
#pragma unroll
    for (int t = 0; t < 4; ++t) {
#pragma unroll
      for (int mf = 0; mf < 4; ++mf) {
        bf16x8 a = *reinterpret_cast<const bf16x8*>(&act0[mf * 16 + lr][t * 32 + lg * 8]);
        acc[mf] = __builtin_amdgcn_mfma_f32_16x16x32_bf16(a, wf[t], acc[mf], 0, 0, 0);
      }
    }
#pragma unroll
    for (int mf = 0; mf < 4; ++mf)
#pragma unroll
      for (int r = 0; r < 4; ++r) {
        int node = node0 + mf * 16 + lg * 4 + r;
        if (node < NN) out[(size_t)node * OUT_D + n0 + lr] = acc[mf][r];
      }
  }
}

extern "C" void kernel_launch(void* const* d_in, const int* in_sizes, int n_in,
                              void* d_out, int out_size, void* d_ws, size_t ws_size,
                              hipStream_t stream) {
  const float* x   = (const float*)d_in[0];
  const int* ei    = (const int*)d_in[1];    // [2, NE]; row 0 = source nodes
  const float* ea  = (const float*)d_in[2];
  const float* u   = (const float*)d_in[3];
  const int* batch = (const int*)d_in[4];
  const float* W1  = (const float*)d_in[5];
  const float* b1  = (const float*)d_in[6];
  const float* W2  = (const float*)d_in[7];
  const float* b2  = (const float*)d_in[8];
  const float* W3  = (const float*)d_in[9];
  const float* b3  = (const float*)d_in[10];
  float* out = (float*)d_out;

  float* sums = (float*)d_ws;                     // NN*48 f32
  float* cnt  = sums + (size_t)NN * EDGE_D;       // NN f32

  hipMemsetAsync(d_ws, 0, ((size_t)NN * EDGE_D + NN) * sizeof(float), stream);

  {
    unsigned total = (unsigned)NE * EDGE_D;
    dim3 g((total + 255) / 256);
    scatter_kernel<<<g, dim3(256), 0, stream>>>(ea, ei, sums, cnt);
  }
  {
    dim3 g((NN + BM - 1) / BM);
    mlp_kernel<<<g, dim3(256), 0, stream>>>(x, sums, cnt, u, batch,
                                            W1, b1, W2, b2, W3, b3, out);
  }
}